// Round 27
// baseline (122.050 us; speedup 1.0000x reference)
//
#include <hip/hip_runtime.h>
#include <hip/hip_bf16.h>
#include <stdint.h>

#define M_TOT 16384
#define N_TOT 3072
#define K_TOT 768

#define BM 256
#define BN 256
#define BK 32
#define NT (K_TOT / BK)   // 24 K-tiles

typedef __attribute__((ext_vector_type(8))) short short8;
typedef __attribute__((ext_vector_type(4))) float f32x4;

__device__ __forceinline__ unsigned short f2bf(float f) {
    union { float f; unsigned u; } v;
    v.f = f;
    unsigned r = v.u + 0x7FFFu + ((v.u >> 16) & 1u);  // round-to-nearest-even
    return (unsigned short)(r >> 16);
}

// ---------------- kernel 1: fused W-prep (512 blocks) + x-cvt (2048 blocks) --
__global__ __launch_bounds__(384) void prep_cvt_kernel(
    const float* __restrict__ Af, const float* __restrict__ Bf,
    const float* __restrict__ Sp, const float* __restrict__ x,
    unsigned short* __restrict__ xb, unsigned short* __restrict__ Wt) {
    __shared__ float a_sh[4][64];
    __shared__ float wrow[4][1160];
    const int tid = threadIdx.x;
    const int b = blockIdx.x;

    if (b < 512) {
        const int m1 = b >> 4;             // 0..31
        const int n10 = (b & 15) * 4;      // 0..60
        if (tid < 256) {
            int rr = tid >> 6, k = tid & 63;
            a_sh[rr][k] = Af[(size_t)(m1 * 64 + n10 + rr) * 64 + k];
        }
        __syncthreads();
        float acc[4][3] = {};
        #pragma unroll 2
        for (int k = 0; k < 64; ++k) {
            const float* brow = Bf + (size_t)k * 1152;
            float b0 = brow[tid], b1 = brow[tid + 384], b2 = brow[tid + 768];
            #pragma unroll
            for (int rr = 0; rr < 4; ++rr) {
                float a = a_sh[rr][k];
                acc[rr][0] = fmaf(a, b0, acc[rr][0]);
                acc[rr][1] = fmaf(a, b1, acc[rr][1]);
                acc[rr][2] = fmaf(a, b2, acc[rr][2]);
            }
        }
        #pragma unroll
        for (int rr = 0; rr < 4; ++rr) {
            wrow[rr][tid] = acc[rr][0];
            wrow[rr][tid + 384] = acc[rr][1];
            wrow[rr][tid + 768] = acc[rr][2];
        }
        __syncthreads();
        if (tid < 192) {
            const int rr = tid / 48, n2 = tid % 48;
            const int c = (n10 + rr) * 48 + n2;
            const int r0 = m1 * 24;
            unsigned w[12];
            #pragma unroll
            for (int t2 = 0; t2 < 12; ++t2) {
                float lo = wrow[rr][(2 * t2) * 48 + n2]
                         + Sp[(size_t)(r0 + 2 * t2) * 3072 + c];
                float hi = wrow[rr][(2 * t2 + 1) * 48 + n2]
                         + Sp[(size_t)(r0 + 2 * t2 + 1) * 3072 + c];
                w[t2] = (unsigned)f2bf(lo) | ((unsigned)f2bf(hi) << 16);
            }
            uint4* d4 = reinterpret_cast<uint4*>(Wt + (size_t)c * 768 + r0);
            d4[0] = (uint4){w[0], w[1], w[2], w[3]};
            d4[1] = (uint4){w[4], w[5], w[6], w[7]};
            d4[2] = (uint4){w[8], w[9], w[10], w[11]};
        }
    } else {
        const int n8 = M_TOT * K_TOT / 8;
        int i = (b - 512) * 384 + tid;
        const int stride = 2048 * 384;
        const float4* xv = reinterpret_cast<const float4*>(x);
        uint4* ov = reinterpret_cast<uint4*>(xb);
        for (; i < n8; i += stride) {
            float4 a = xv[2 * i], c = xv[2 * i + 1];
            uint4 o;
            o.x = (unsigned)f2bf(a.x) | ((unsigned)f2bf(a.y) << 16);
            o.y = (unsigned)f2bf(a.z) | ((unsigned)f2bf(a.w) << 16);
            o.z = (unsigned)f2bf(c.x) | ((unsigned)f2bf(c.y) << 16);
            o.w = (unsigned)f2bf(c.z) | ((unsigned)f2bf(c.w) << 16);
            ov[i] = o;
        }
    }
}

// ---------------- kernel 2: R18 GEMM (terminal: 121.4us total) ---------------
// A [16384][768] bf16; Bt [3072][768] bf16; C = A@Bt^T + bias.
// 16x16x32 MFMA, one-phase-lag read pipeline, 4-buffer rotation, counted
// vmcnt(4) ladder (proven minimal), ONE barrier/K-tile, swapped-operand MFMA
// -> float4 stores.  Session ledger (R4-R23, 14 mechanisms + paper-refuted
// M-split store-overlap): loop floor = LDS(1476cyc) + MFMA(1241cyc) per tile
// serialized at 2 waves/SIMD (128-reg accumulator).  Reproduced at
// 121.4/121.5/121.7/121.6/121.8us.
__device__ __forceinline__ void gld16(const void* g, void* l) {
    __builtin_amdgcn_global_load_lds(
        (const __attribute__((address_space(1))) void*)g,
        (__attribute__((address_space(3))) void*)l, 16, 0, 0);
}

__global__ __launch_bounds__(512, 2) void gemm_bt_kernel(
    const unsigned short* __restrict__ A, const unsigned short* __restrict__ Bt,
    const float* __restrict__ bias, float* __restrict__ C) {
    __shared__ unsigned short As[4][BM * BK];
    __shared__ unsigned short Bs[4][BN * BK];

    const int tid = threadIdx.x;
    const int lane = tid & 63;
    const int wid = tid >> 6;      // 0..7
    const int wr = wid >> 2;       // 0..1  (M half)
    const int wc = wid & 3;        // 0..3  (N quarter)

    // XCD-aware swizzle: 768 blocks = 8 XCDs x 96
    const int wg = (blockIdx.x & 7) * 96 + (blockIdx.x >> 3);
    const int bm = wg / (N_TOT / BN), bn = wg % (N_TOT / BN);
    const int brow = bm * BM, bcol = bn * BN;

    const int srow = tid >> 2;                                   // 0..127
    const int soff = (((tid & 3) ^ ((tid >> 3) & 3)) << 4);      // bytes
    const char* pA = (const char*)A + ((size_t)(brow + srow) * K_TOT) * 2 + soff;
    const char* pB = (const char*)Bt + ((size_t)(bcol + srow) * K_TOT) * 2 + soff;
    const size_t row128 = (size_t)128 * K_TOT * 2;
    const int tid16 = tid * 16;

#define STAGE_AH(u) do { const char* s_ = pA + (size_t)(u) * (BK * 2);           \
        gld16(s_,          (char*)&As[(u) & 3][0] + tid16);                      \
        gld16(s_ + row128, (char*)&As[(u) & 3][0] + tid16 + 8192); } while (0)
#define STAGE_BH(u) do { const char* s_ = pB + (size_t)(u) * (BK * 2);           \
        gld16(s_,          (char*)&Bs[(u) & 3][0] + tid16);                      \
        gld16(s_ + row128, (char*)&Bs[(u) & 3][0] + tid16 + 8192); } while (0)

    const int la = lane & 15;
    const int g4 = lane >> 4;
    const int swb = ((g4 ^ ((lane >> 1) & 3)) << 4);   // byte in row
#define FRAG_A(bu, r) (*(const short8*)((const char*)&As[bu][0] + (r) * 64 + swb))
#define FRAG_B(bu, r) (*(const short8*)((const char*)&Bs[bu][0] + (r) * 64 + swb))

    f32x4 acc[8][4];
    #pragma unroll
    for (int m = 0; m < 8; ++m)
        #pragma unroll
        for (int n = 0; n < 4; ++n)
            acc[m][n] = (f32x4){0.f, 0.f, 0.f, 0.f};

    const int arow = wr * 128;
    const int bcolw = wc * 64;

    short8 bE[4], bO[4], aLo[4], aHi[4];

    // prologue: stage tiles 0,1,2; tiles 0,1 resident; read tile-0 b/aLo.
    STAGE_AH(0); STAGE_BH(0);
    STAGE_AH(1); STAGE_BH(1);
    STAGE_AH(2); STAGE_BH(2);
    asm volatile("s_waitcnt vmcnt(4)" ::: "memory");
    __builtin_amdgcn_s_barrier();
    #pragma unroll
    for (int n = 0; n < 4; ++n) bE[n] = FRAG_B(0, bcolw + n * 16 + la);
    #pragma unroll
    for (int m = 0; m < 4; ++m) aLo[m] = FRAG_A(0, arow + m * 16 + la);
    __builtin_amdgcn_sched_barrier(0);

    // tile body: bc = current b set (tile t), bnx = next b set (loads t+1)
    auto tile_body = [&](int t, short8 (&bc)[4], short8 (&bnx)[4]) {
        const int bu = t & 3;
        // ===== phase A: issue aHi[t] reads + STAGE_A(t+3); MFMA m0-3 =========
        #pragma unroll
        for (int m = 0; m < 4; ++m) aHi[m] = FRAG_A(bu, arow + 64 + m * 16 + la);
        if (t < NT - 3) STAGE_AH(t + 3);
        __builtin_amdgcn_sched_barrier(0);
        __builtin_amdgcn_s_setprio(1);
        #pragma unroll
        for (int m = 0; m < 4; ++m)            // auto lgkmcnt(4): aHi in flight
            #pragma unroll
            for (int n = 0; n < 4; ++n)
                acc[m][n] = __builtin_amdgcn_mfma_f32_16x16x32_bf16(
                    bc[n], aLo[m], acc[m][n], 0, 0, 0);
        __builtin_amdgcn_s_setprio(0);
        // ===== phase B: issue b/aLo[t+1] reads + STAGE_B(t+3); MFMA m4-7 =====
        if (t < NT - 1) {
            const int bu1 = (t + 1) & 3;       // published at tile t-1's barrier
            #pragma unroll
            for (int n = 0; n < 4; ++n) bnx[n] = FRAG_B(bu1, bcolw + n * 16 + la);
            #pragma unroll
            for (int m = 0; m < 4; ++m) aLo[m] = FRAG_A(bu1, arow + m * 16 + la);
        }
        if (t < NT - 3) STAGE_BH(t + 3);
        __builtin_amdgcn_sched_barrier(0);
        // rendezvous (only barrier of the tile): publish stages of t+1/t+2
        if (t < NT - 3)       asm volatile("s_waitcnt vmcnt(4)" ::: "memory");
        else if (t == NT - 3) asm volatile("s_waitcnt vmcnt(0)" ::: "memory");
        __builtin_amdgcn_s_barrier();
        __builtin_amdgcn_s_setprio(1);
        #pragma unroll
        for (int m = 0; m < 4; ++m)            // auto lgkmcnt(8): next in flight
            #pragma unroll
            for (int n = 0; n < 4; ++n)
                acc[4 + m][n] = __builtin_amdgcn_mfma_f32_16x16x32_bf16(
                    bc[n], aHi[m], acc[4 + m][n], 0, 0, 0);
        __builtin_amdgcn_s_setprio(0);
    };

    #pragma unroll 1
    for (int tt = 0; tt < NT; tt += 2) {       // NT=24 even; b-set parity swap
        tile_body(tt, bE, bO);
        tile_body(tt + 1, bO, bE);
    }

    // ---- epilogue: lane owns M-row (la) x 4 N-cols (g4*4+j) -> float4 stores
    #pragma unroll
    for (int n = 0; n < 4; ++n) {
        const int gc = bcol + bcolw + n * 16 + g4 * 4;
        const f32x4 bv = *reinterpret_cast<const f32x4*>(&bias[gc]);
        #pragma unroll
        for (int m = 0; m < 8; ++m) {
            const int gr = brow + arow + m * 16 + la;
            f32x4 o = {acc[m][n][0] + bv[0], acc[m][n][1] + bv[1],
                       acc[m][n][2] + bv[2], acc[m][n][3] + bv[3]};
            *reinterpret_cast<f32x4*>(&C[(size_t)gr * N_TOT + gc]) = o;
        }
    }
#undef STAGE_AH
#undef STAGE_BH
#undef FRAG_A
#undef FRAG_B
}

extern "C" void kernel_launch(void* const* d_in, const int* in_sizes, int n_in,
                              void* d_out, int out_size, void* d_ws, size_t ws_size,
                              hipStream_t stream) {
    const float* x    = (const float*)d_in[0];
    const float* Af   = (const float*)d_in[1];  // [2048][64]
    const float* Bf   = (const float*)d_in[2];  // [64][1152]
    const float* Sp   = (const float*)d_in[3];  // [768][3072]
    const float* bias = (const float*)d_in[4];  // [3072]
    float* out = (float*)d_out;

    unsigned short* xb = (unsigned short*)d_ws;                 // 25,165,824 B
    unsigned short* wt = xb + (size_t)M_TOT * K_TOT;            // + 4,718,592 B

    hipLaunchKernelGGL(prep_cvt_kernel, dim3(512 + 2048), dim3(384), 0, stream,
                       Af, Bf, Sp, x, xb, wt);
    hipLaunchKernelGGL(gemm_bt_kernel,
                       dim3((M_TOT / BM) * (N_TOT / BN)), dim3(512),
                       0, stream, xb, wt, bias, out);
}

// Round 28
// 121.116 us; speedup vs baseline: 1.0077x; 1.0077x over previous
//
#include <hip/hip_runtime.h>
#include <hip/hip_bf16.h>
#include <stdint.h>

#define M_TOT 16384
#define N_TOT 3072
#define K_TOT 768

#define BM 256
#define BN 256
#define BK 32
#define NT (K_TOT / BK)   // 24 K-tiles

typedef __attribute__((ext_vector_type(8))) short short8;
typedef __attribute__((ext_vector_type(4))) float f32x4;

__device__ __forceinline__ unsigned short f2bf(float f) {
    union { float f; unsigned u; } v;
    v.f = f;
    unsigned r = v.u + 0x7FFFu + ((v.u >> 16) & 1u);  // round-to-nearest-even
    return (unsigned short)(r >> 16);
}

// ---------------- kernel 1: fused W-prep (512 blocks) + x-cvt (2048 blocks) --
__global__ __launch_bounds__(384) void prep_cvt_kernel(
    const float* __restrict__ Af, const float* __restrict__ Bf,
    const float* __restrict__ Sp, const float* __restrict__ x,
    unsigned short* __restrict__ xb, unsigned short* __restrict__ Wt) {
    __shared__ float a_sh[4][64];
    __shared__ float wrow[4][1160];
    const int tid = threadIdx.x;
    const int b = blockIdx.x;

    if (b < 512) {
        const int m1 = b >> 4;             // 0..31
        const int n10 = (b & 15) * 4;      // 0..60
        if (tid < 256) {
            int rr = tid >> 6, k = tid & 63;
            a_sh[rr][k] = Af[(size_t)(m1 * 64 + n10 + rr) * 64 + k];
        }
        __syncthreads();
        float acc[4][3] = {};
        #pragma unroll 2
        for (int k = 0; k < 64; ++k) {
            const float* brow = Bf + (size_t)k * 1152;
            float b0 = brow[tid], b1 = brow[tid + 384], b2 = brow[tid + 768];
            #pragma unroll
            for (int rr = 0; rr < 4; ++rr) {
                float a = a_sh[rr][k];
                acc[rr][0] = fmaf(a, b0, acc[rr][0]);
                acc[rr][1] = fmaf(a, b1, acc[rr][1]);
                acc[rr][2] = fmaf(a, b2, acc[rr][2]);
            }
        }
        #pragma unroll
        for (int rr = 0; rr < 4; ++rr) {
            wrow[rr][tid] = acc[rr][0];
            wrow[rr][tid + 384] = acc[rr][1];
            wrow[rr][tid + 768] = acc[rr][2];
        }
        __syncthreads();
        if (tid < 192) {
            const int rr = tid / 48, n2 = tid % 48;
            const int c = (n10 + rr) * 48 + n2;
            const int r0 = m1 * 24;
            unsigned w[12];
            #pragma unroll
            for (int t2 = 0; t2 < 12; ++t2) {
                float lo = wrow[rr][(2 * t2) * 48 + n2]
                         + Sp[(size_t)(r0 + 2 * t2) * 3072 + c];
                float hi = wrow[rr][(2 * t2 + 1) * 48 + n2]
                         + Sp[(size_t)(r0 + 2 * t2 + 1) * 3072 + c];
                w[t2] = (unsigned)f2bf(lo) | ((unsigned)f2bf(hi) << 16);
            }
            uint4* d4 = reinterpret_cast<uint4*>(Wt + (size_t)c * 768 + r0);
            d4[0] = (uint4){w[0], w[1], w[2], w[3]};
            d4[1] = (uint4){w[4], w[5], w[6], w[7]};
            d4[2] = (uint4){w[8], w[9], w[10], w[11]};
        }
    } else {
        const int n8 = M_TOT * K_TOT / 8;
        int i = (b - 512) * 384 + tid;
        const int stride = 2048 * 384;
        const float4* xv = reinterpret_cast<const float4*>(x);
        uint4* ov = reinterpret_cast<uint4*>(xb);
        for (; i < n8; i += stride) {
            float4 a = xv[2 * i], c = xv[2 * i + 1];
            uint4 o;
            o.x = (unsigned)f2bf(a.x) | ((unsigned)f2bf(a.y) << 16);
            o.y = (unsigned)f2bf(a.z) | ((unsigned)f2bf(a.w) << 16);
            o.z = (unsigned)f2bf(c.x) | ((unsigned)f2bf(c.y) << 16);
            o.w = (unsigned)f2bf(c.z) | ((unsigned)f2bf(c.w) << 16);
            ov[i] = o;
        }
    }
}

// ---------------- kernel 2: R18 GEMM (terminal: 121.4us total) ---------------
// A [16384][768] bf16; Bt [3072][768] bf16; C = A@Bt^T + bias.
// 16x16x32 MFMA, one-phase-lag read pipeline, 4-buffer rotation, counted
// vmcnt(4) ladder (proven minimal), ONE barrier/K-tile, swapped-operand MFMA
// -> float4 stores.  Session ledger (R4-R23, 14 mechanisms + ledger-refuted
// vmcnt relaxation and M-split store-overlap): loop floor = LDS(1476cyc) +
// MFMA(1241cyc) per tile serialized at 2 waves/SIMD (128-reg accumulator).
// Reproduced at 121.4/121.5/121.7/121.6/121.8/122.0us.
__device__ __forceinline__ void gld16(const void* g, void* l) {
    __builtin_amdgcn_global_load_lds(
        (const __attribute__((address_space(1))) void*)g,
        (__attribute__((address_space(3))) void*)l, 16, 0, 0);
}

__global__ __launch_bounds__(512, 2) void gemm_bt_kernel(
    const unsigned short* __restrict__ A, const unsigned short* __restrict__ Bt,
    const float* __restrict__ bias, float* __restrict__ C) {
    __shared__ unsigned short As[4][BM * BK];
    __shared__ unsigned short Bs[4][BN * BK];

    const int tid = threadIdx.x;
    const int lane = tid & 63;
    const int wid = tid >> 6;      // 0..7
    const int wr = wid >> 2;       // 0..1  (M half)
    const int wc = wid & 3;        // 0..3  (N quarter)

    // XCD-aware swizzle: 768 blocks = 8 XCDs x 96
    const int wg = (blockIdx.x & 7) * 96 + (blockIdx.x >> 3);
    const int bm = wg / (N_TOT / BN), bn = wg % (N_TOT / BN);
    const int brow = bm * BM, bcol = bn * BN;

    const int srow = tid >> 2;                                   // 0..127
    const int soff = (((tid & 3) ^ ((tid >> 3) & 3)) << 4);      // bytes
    const char* pA = (const char*)A + ((size_t)(brow + srow) * K_TOT) * 2 + soff;
    const char* pB = (const char*)Bt + ((size_t)(bcol + srow) * K_TOT) * 2 + soff;
    const size_t row128 = (size_t)128 * K_TOT * 2;
    const int tid16 = tid * 16;

#define STAGE_AH(u) do { const char* s_ = pA + (size_t)(u) * (BK * 2);           \
        gld16(s_,          (char*)&As[(u) & 3][0] + tid16);                      \
        gld16(s_ + row128, (char*)&As[(u) & 3][0] + tid16 + 8192); } while (0)
#define STAGE_BH(u) do { const char* s_ = pB + (size_t)(u) * (BK * 2);           \
        gld16(s_,          (char*)&Bs[(u) & 3][0] + tid16);                      \
        gld16(s_ + row128, (char*)&Bs[(u) & 3][0] + tid16 + 8192); } while (0)

    const int la = lane & 15;
    const int g4 = lane >> 4;
    const int swb = ((g4 ^ ((lane >> 1) & 3)) << 4);   // byte in row
#define FRAG_A(bu, r) (*(const short8*)((const char*)&As[bu][0] + (r) * 64 + swb))
#define FRAG_B(bu, r) (*(const short8*)((const char*)&Bs[bu][0] + (r) * 64 + swb))

    f32x4 acc[8][4];
    #pragma unroll
    for (int m = 0; m < 8; ++m)
        #pragma unroll
        for (int n = 0; n < 4; ++n)
            acc[m][n] = (f32x4){0.f, 0.f, 0.f, 0.f};

    const int arow = wr * 128;
    const int bcolw = wc * 64;

    short8 bE[4], bO[4], aLo[4], aHi[4];

    // prologue: stage tiles 0,1,2; tiles 0,1 resident; read tile-0 b/aLo.
    STAGE_AH(0); STAGE_BH(0);
    STAGE_AH(1); STAGE_BH(1);
    STAGE_AH(2); STAGE_BH(2);
    asm volatile("s_waitcnt vmcnt(4)" ::: "memory");
    __builtin_amdgcn_s_barrier();
    #pragma unroll
    for (int n = 0; n < 4; ++n) bE[n] = FRAG_B(0, bcolw + n * 16 + la);
    #pragma unroll
    for (int m = 0; m < 4; ++m) aLo[m] = FRAG_A(0, arow + m * 16 + la);
    __builtin_amdgcn_sched_barrier(0);

    // tile body: bc = current b set (tile t), bnx = next b set (loads t+1)
    auto tile_body = [&](int t, short8 (&bc)[4], short8 (&bnx)[4]) {
        const int bu = t & 3;
        // ===== phase A: issue aHi[t] reads + STAGE_A(t+3); MFMA m0-3 =========
        #pragma unroll
        for (int m = 0; m < 4; ++m) aHi[m] = FRAG_A(bu, arow + 64 + m * 16 + la);
        if (t < NT - 3) STAGE_AH(t + 3);
        __builtin_amdgcn_sched_barrier(0);
        __builtin_amdgcn_s_setprio(1);
        #pragma unroll
        for (int m = 0; m < 4; ++m)            // auto lgkmcnt(4): aHi in flight
            #pragma unroll
            for (int n = 0; n < 4; ++n)
                acc[m][n] = __builtin_amdgcn_mfma_f32_16x16x32_bf16(
                    bc[n], aLo[m], acc[m][n], 0, 0, 0);
        __builtin_amdgcn_s_setprio(0);
        // ===== phase B: issue b/aLo[t+1] reads + STAGE_B(t+3); MFMA m4-7 =====
        if (t < NT - 1) {
            const int bu1 = (t + 1) & 3;       // published at tile t-1's barrier
            #pragma unroll
            for (int n = 0; n < 4; ++n) bnx[n] = FRAG_B(bu1, bcolw + n * 16 + la);
            #pragma unroll
            for (int m = 0; m < 4; ++m) aLo[m] = FRAG_A(bu1, arow + m * 16 + la);
        }
        if (t < NT - 3) STAGE_BH(t + 3);
        __builtin_amdgcn_sched_barrier(0);
        // rendezvous (only barrier of the tile): publish stages of t+1/t+2
        if (t < NT - 3)       asm volatile("s_waitcnt vmcnt(4)" ::: "memory");
        else if (t == NT - 3) asm volatile("s_waitcnt vmcnt(0)" ::: "memory");
        __builtin_amdgcn_s_barrier();
        __builtin_amdgcn_s_setprio(1);
        #pragma unroll
        for (int m = 0; m < 4; ++m)            // auto lgkmcnt(8): next in flight
            #pragma unroll
            for (int n = 0; n < 4; ++n)
                acc[4 + m][n] = __builtin_amdgcn_mfma_f32_16x16x32_bf16(
                    bc[n], aHi[m], acc[4 + m][n], 0, 0, 0);
        __builtin_amdgcn_s_setprio(0);
    };

    #pragma unroll 1
    for (int tt = 0; tt < NT; tt += 2) {       // NT=24 even; b-set parity swap
        tile_body(tt, bE, bO);
        tile_body(tt + 1, bO, bE);
    }

    // ---- epilogue: lane owns M-row (la) x 4 N-cols (g4*4+j) -> float4 stores
    #pragma unroll
    for (int n = 0; n < 4; ++n) {
        const int gc = bcol + bcolw + n * 16 + g4 * 4;
        const f32x4 bv = *reinterpret_cast<const f32x4*>(&bias[gc]);
        #pragma unroll
        for (int m = 0; m < 8; ++m) {
            const int gr = brow + arow + m * 16 + la;
            f32x4 o = {acc[m][n][0] + bv[0], acc[m][n][1] + bv[1],
                       acc[m][n][2] + bv[2], acc[m][n][3] + bv[3]};
            *reinterpret_cast<f32x4*>(&C[(size_t)gr * N_TOT + gc]) = o;
        }
    }
#undef STAGE_AH
#undef STAGE_BH
#undef FRAG_A
#undef FRAG_B
}

extern "C" void kernel_launch(void* const* d_in, const int* in_sizes, int n_in,
                              void* d_out, int out_size, void* d_ws, size_t ws_size,
                              hipStream_t stream) {
    const float* x    = (const float*)d_in[0];
    const float* Af   = (const float*)d_in[1];  // [2048][64]
    const float* Bf   = (const float*)d_in[2];  // [64][1152]
    const float* Sp   = (const float*)d_in[3];  // [768][3072]
    const float* bias = (const float*)d_in[4];  // [3072]
    float* out = (float*)d_out;

    unsigned short* xb = (unsigned short*)d_ws;                 // 25,165,824 B
    unsigned short* wt = xb + (size_t)M_TOT * K_TOT;            // + 4,718,592 B

    hipLaunchKernelGGL(prep_cvt_kernel, dim3(512 + 2048), dim3(384), 0, stream,
                       Af, Bf, Sp, x, xb, wt);
    hipLaunchKernelGGL(gemm_bt_kernel,
                       dim3((M_TOT / BM) * (N_TOT / BN)), dim3(512),
                       0, stream, xb, wt, bias, out);
}